// Round 18
// baseline (219.804 us; speedup 1.0000x reference)
//
#include <hip/hip_runtime.h>

#define SS 2048
#define DD 1024
#define HH 16
#define HDIM 64
#define BB 2
#define FFD 4096
#define MR (BB*SS)   // 4096 rows
#define QKVLD 3072   // fused qkv row stride

typedef __bf16 bf16;
typedef __bf16 bf16x4 __attribute__((ext_vector_type(4)));
typedef __bf16 bf16x8 __attribute__((ext_vector_type(8)));
typedef float f32x4 __attribute__((ext_vector_type(4)));

struct P4 { bf16* p[4]; };
struct TP4 { const float* src[4]; bf16* dst[4]; float scale[4]; };

__device__ inline f32x4 mfma32(bf16x8 a, bf16x8 b, f32x4 c) {
  return __builtin_amdgcn_mfma_f32_16x16x32_bf16(a, b, c, 0, 0, 0);
}

__device__ inline void gload_lds16(const void* g, void* l) {
  __builtin_amdgcn_global_load_lds(
      (const __attribute__((address_space(1))) void*)g,
      (__attribute__((address_space(3))) void*)l, 16, 0, 0);
}

// raw v_exp_f32 (2^x) — no libm denormal fixup (exp2f regressed R9; confirmed R10)
#if defined(__has_builtin)
#if __has_builtin(__builtin_amdgcn_exp2f)
#define HAVE_EXP2_BUILTIN 1
#endif
#endif
__device__ inline float fast_exp2(float x) {
#ifdef HAVE_EXP2_BUILTIN
  return __builtin_amdgcn_exp2f(x);
#else
  float r; asm("v_exp_f32 %0, %1" : "=v"(r) : "v"(x)); return r;
#endif
}

// ---------------- fp32 -> bf16 elementwise ----------------
__global__ __launch_bounds__(256)
void cvt_bf16_kernel(const float* __restrict__ in, bf16* __restrict__ out, int n) {
  int i = (blockIdx.x * 256 + threadIdx.x) * 4;
  if (i >= n) return;
  float4 v = *(const float4*)(in + i);
  bf16x4 o;
  o[0] = (bf16)v.x; o[1] = (bf16)v.y; o[2] = (bf16)v.z; o[3] = (bf16)v.w;
  *(bf16x4*)(out + i) = o;
}

// ---------------- concat bias qkv (bq pre-scaled by 0.125*log2e) ----------------
__global__ __launch_bounds__(256)
void concat_bias_kernel(const float* __restrict__ bq, const float* __restrict__ bk,
                        const float* __restrict__ bv, float* __restrict__ out) {
  int i = blockIdx.x * 256 + threadIdx.x;
  const float K2 = 0.18033688f;
  out[i] = i < 1024 ? bq[i] * K2 : (i < 2048 ? bk[i - 1024] : bv[i - 2048]);
}

// ---- 4x fused W [1024,1024] fp32 -> Wt bf16, optional per-matrix scale ----
__global__ __launch_bounds__(256)
void transpose_w4_kernel(TP4 t) {
  __shared__ float tl[32][33];
  const float* W = t.src[blockIdx.z];
  bf16* Wt = t.dst[blockIdx.z];
  const float sc = t.scale[blockIdx.z];
  int tx = threadIdx.x & 31, ty = threadIdx.x >> 5;  // 32 x 8
  int n0 = blockIdx.x * 32, k0 = blockIdx.y * 32;
  #pragma unroll
  for (int i = 0; i < 4; ++i)
    tl[ty + i*8][tx] = W[(size_t)(k0 + ty + i*8) * DD + n0 + tx];
  __syncthreads();
  #pragma unroll
  for (int i = 0; i < 4; ++i)
    Wt[(size_t)(n0 + ty + i*8) * DD + k0 + tx] = (bf16)(tl[tx][ty + i*8] * sc);
}

// ---------------- W [K,N] fp32 -> Wt [N,K] bf16 (W1/W2) ----------------
__global__ __launch_bounds__(256)
void transpose_w_kernel(const float* __restrict__ W, bf16* __restrict__ Wt,
                        int K, int N) {
  __shared__ float t[32][33];
  int tx = threadIdx.x & 31, ty = threadIdx.x >> 5;  // 32 x 8
  int n0 = blockIdx.x * 32, k0 = blockIdx.y * 32;
  #pragma unroll
  for (int i = 0; i < 4; ++i)
    t[ty + i*8][tx] = W[(size_t)(k0 + ty + i*8) * N + n0 + tx];
  __syncthreads();
  #pragma unroll
  for (int i = 0; i < 4; ++i)
    Wt[(size_t)(n0 + ty + i*8) * K + k0 + tx] = (bf16)t[tx][ty + i*8];
}

// ---------------- V (cols of qkv2d) -> Vt [B,H,HD,S] bf16 ----------------
__global__ __launch_bounds__(256)
void transpose_v_kernel(const bf16* __restrict__ V2d, bf16* __restrict__ Vt) {
  __shared__ bf16 t[32][33];
  int tx = threadIdx.x & 31, ty = threadIdx.x >> 5;
  int s0 = blockIdx.x * 32, d0 = blockIdx.y * 32;
  int bh = blockIdx.z;
  int b = bh >> 4, h = bh & 15;
  #pragma unroll
  for (int i = 0; i < 4; ++i)
    t[ty + i*8][tx] = V2d[(size_t)(b*SS + s0 + ty + i*8) * QKVLD + h*HDIM + d0 + tx];
  __syncthreads();
  #pragma unroll
  for (int i = 0; i < 4; ++i)
    Vt[((size_t)bh*HDIM + d0 + ty + i*8) * SS + s0 + tx] = t[tx][ty + i*8];
}

// ======== gemm_h: 128(M)x256(N) tile, BK=32, 8 waves, 48KB LDS dbuf ========
// 2 blocks/CU (4 waves/SIMD): one block's prologue/epilogue/barriers overlap
// the other's MFMA. m97-proven sync: frag reads -> stage(t+1) -> MFMA ->
// __syncthreads (implicit vmcnt drain). 8 ds_read_b128 per wave per K-tile
// for 16 MFMA. Swizzle phys_slot = s ^ (row&3) (involution, 2 lanes/bank).
// SPLITK>1: blockIdx.z = K-chunk, bf16 partial (no bias/relu) to part.p[bz].
template<int OUT_BF16, int RELU, int SPLITK>
__global__ __launch_bounds__(512)
void gemm_h(const bf16* __restrict__ A, const bf16* __restrict__ Bt,
            const float* __restrict__ bias, void* __restrict__ Cout,
            P4 part, int Ndim, int Kdim) {
  __shared__ bf16 Asm[2][128 * 32];   // 8KB x2
  __shared__ bf16 Bsm[2][256 * 32];   // 16KB x2 => 48KB
  const int gx = gridDim.x, gy = gridDim.y;
  const int gxy = gx * gy;
  const int nwg = gxy * gridDim.z;
  const int lin = (blockIdx.z * gy + blockIdx.y) * gx + blockIdx.x;
  const int swz = (lin & 7) * (nwg >> 3) + (lin >> 3);
  int bz = 0, rem = swz;
  if (SPLITK > 1) { bz = swz / gxy; rem = swz - bz * gxy; }
  const int by = rem / gx, bx = rem - by * gx;
  const int m0 = by * 128, n0 = bx * 256;
  const int tid = threadIdx.x;
  const int wave = tid >> 6, lane = tid & 63;
  const int g = lane >> 4, r = lane & 15;
  const int wr = wave >> 2, wn = wave & 3;   // 2M x 4N -> per-wave 64x64
  const int kstart = bz * (Kdim / SPLITK);

  const int lrow = lane >> 2;                 // 0..15
  const int lslot = (lane & 3) ^ (lrow & 3);  // pre-swizzled global slot
  const bf16* Ag = A + (size_t)(m0 + wave * 16 + lrow) * Kdim + kstart + lslot * 8;
  const bf16* Bg0 = Bt + (size_t)(n0 + wave * 32 + lrow) * Kdim + kstart + lslot * 8;
  const bf16* Bg1 = Bg0 + (size_t)16 * Kdim;

  f32x4 acc[4][4] = {};
  const int NT = (Kdim / SPLITK) >> 5;

  auto stage = [&](int t) {
    const int kb = t << 5;
    bf16* Ad = Asm[t & 1] + wave * 512;          // wave's 16 rows x 32
    bf16* Bd = Bsm[t & 1] + wave * 1024;         // wave's 32 rows x 32
    gload_lds16(Ag + kb, Ad);
    gload_lds16(Bg0 + kb, Bd);
    gload_lds16(Bg1 + kb, Bd + 512);
  };

  stage(0);
  __syncthreads();

  for (int t = 0; t < NT; ++t) {
    const bf16* Ab = Asm[t & 1];
    const bf16* Bb = Bsm[t & 1];
    bf16x8 af[4], bfr[4];
    #pragma unroll
    for (int i = 0; i < 4; ++i) {
      const int row = wr * 64 + i * 16 + r;
      af[i] = *(const bf16x8*)(Ab + row * 32 + ((g ^ (r & 3)) * 8));
    }
    #pragma unroll
    for (int i = 0; i < 4; ++i) {
      const int rowb = wn * 64 + i * 16 + r;
      bfr[i] = *(const bf16x8*)(Bb + rowb * 32 + ((g ^ (r & 3)) * 8));
    }
    if (t + 1 < NT) stage(t + 1);
    __builtin_amdgcn_s_setprio(1);
    #pragma unroll
    for (int i = 0; i < 4; ++i)
      #pragma unroll
      for (int jn = 0; jn < 4; ++jn)
        acc[i][jn] = mfma32(af[i], bfr[jn], acc[i][jn]);
    __builtin_amdgcn_s_setprio(0);
    __syncthreads();
  }

  #pragma unroll
  for (int mi = 0; mi < 4; ++mi) {
    #pragma unroll
    for (int ni = 0; ni < 4; ++ni) {
      const int col = n0 + wn * 64 + ni * 16 + r;
      const float bv = (SPLITK > 1) ? 0.f : bias[col];
      #pragma unroll
      for (int jj = 0; jj < 4; ++jj) {
        const int row = m0 + wr * 64 + mi * 16 + g * 4 + jj;
        float v = acc[mi][ni][jj] + bv;
        if (RELU) v = fmaxf(v, 0.f);
        if (SPLITK > 1) part.p[bz][(size_t)row * Ndim + col] = (bf16)v;
        else if (OUT_BF16) ((bf16*)Cout)[(size_t)row * Ndim + col] = (bf16)v;
        else               ((float*)Cout)[(size_t)row * Ndim + col] = v;
      }
    }
  }
}

// ---------------- flash attention v7: Q pre-scaled (scores already log2) ----------------
__global__ __launch_bounds__(256)
void attn_kernel(const bf16* __restrict__ Q2d, const bf16* __restrict__ K2d,
                 const bf16* __restrict__ Vt, bf16* __restrict__ ctx) {
  __shared__ bf16 Ks[2 * 4096];   // 2 bufs x [2 halves][64][32]
  __shared__ bf16 Vs[2 * 4096];
  const int tid = threadIdx.x;
  const int wave = tid >> 6;
  const int lane = tid & 63;
  const int g = lane >> 4, r = lane & 15;
  const int lin = blockIdx.y * gridDim.x + blockIdx.x;   // 0..511
  const int swz = (lin & 7) * 64 + (lin >> 3);
  const int p = swz & 15;            // pair index 0..15
  const int bh = swz >> 4;           // 0..31
  const int b = bh >> 4, h = bh & 15;

  const int strow = wave * 16 + (lane >> 2);              // 0..63
  const int lslot = (lane & 3) ^ ((lane >> 3) & 3);       // pre-swizzled global slot
  const bf16* srcK0 = K2d + (size_t)(b*SS + strow) * QKVLD + h*HDIM + lslot * 8;
  const bf16* srcK1 = srcK0 + 32;
  const bf16* srcV0 = Vt + ((size_t)bh*HDIM + strow) * SS + lslot * 8;
  const bf16* srcV1 = srcV0 + 32;

  auto sw = [](int row, int s) { return row * 32 + ((s ^ ((row >> 1) & 3)) * 8); };

  const int kr0 = 8 * (r >> 2) + (r & 3);      // permuted K row for S^T frag
  const int oKa0 = sw(kr0,      g), oKb0 = 2048 + oKa0;
  const int oKa1 = sw(kr0 +  4, g), oKb1 = 2048 + oKa1;
  const int oKa2 = sw(kr0 + 32, g), oKb2 = 2048 + oKa2;
  const int oKa3 = sw(kr0 + 36, g), oKb3 = 2048 + oKa3;
  int oV[4];
  #pragma unroll
  for (int c = 0; c < 4; ++c) oV[c] = sw(c * 16 + r, g);

  bf16x8 onesf;
  #pragma unroll
  for (int j = 0; j < 8; ++j) onesf[j] = (bf16)1.0f;

  #pragma unroll
  for (int tt = 0; tt < 2; ++tt) {
    const int tile = tt ? (31 - p) : p;
    const int q0 = tile * 64 + wave * 16;
    const int qg = q0 + r;
    const bf16* qp = Q2d + (size_t)(b*SS + q0 + r) * QKVLD + h * HDIM;
    const bf16x8 qf0 = *(const bf16x8*)(qp + g * 8);
    const bf16x8 qf1 = *(const bf16x8*)(qp + 32 + g * 8);
    f32x4 ov[4] = {};
    f32x4 lacc = {};                // row-sum l via ones-column MFMA
    const int nst = tile + 1;
    {
      bf16* kb = Ks + wave * 512;
      bf16* vb = Vs + wave * 512;
      gload_lds16(srcK0, kb);
      gload_lds16(srcK1, kb + 2048);
      gload_lds16(srcV0, vb);
      gload_lds16(srcV1, vb + 2048);
    }
    __syncthreads();
    int cur = 0;
    for (int st = 0; st < nst; ++st) {
      const int k0 = st * 64;
      if (st + 1 < nst) {
        const int kn = k0 + 64;
        bf16* kb = Ks + (cur ^ 1) * 4096 + wave * 512;
        bf16* vb = Vs + (cur ^ 1) * 4096 + wave * 512;
        gload_lds16(srcK0 + (size_t)kn * QKVLD, kb);
        gload_lds16(srcK1 + (size_t)kn * QKVLD, kb + 2048);
        gload_lds16(srcV0 + kn, vb);
        gload_lds16(srcV1 + kn, vb + 2048);
      }
      const bf16* Kb = Ks + cur * 4096;
      const bf16* Vb = Vs + cur * 4096;
      f32x4 c0 = {}, c1 = {}, c2 = {}, c3 = {};
      __builtin_amdgcn_s_setprio(1);
      c0 = mfma32(*(const bf16x8*)(Kb + oKa0), qf0, c0);
      c1 = mfma32(*(const bf16x8*)(Kb + oKa1), qf0, c1);
      c2 = mfma32(*(const bf16x8*)(Kb + oKa2), qf0, c2);
      c3 = mfma32(*(const bf16x8*)(Kb + oKa3), qf0, c3);
      c0 = mfma32(*(const bf16x8*)(Kb + oKb0), qf1, c0);
      c1 = mfma32(*(const bf16x8*)(Kb + oKb1), qf1, c1);
      c2 = mfma32(*(const bf16x8*)(Kb + oKb2), qf1, c2);
      c3 = mfma32(*(const bf16x8*)(Kb + oKb3), qf1, c3);
      __builtin_amdgcn_s_setprio(0);
      float p0[4], p1[4], p2[4], p3[4];
      const bool need_mask = (k0 + 63 > qg);
      #pragma unroll
      for (int j = 0; j < 4; ++j) {
        float s0 = c0[j];
        float s1 = c1[j];
        float s2 = c2[j];
        float s3 = c3[j];
        if (need_mask) {
          if (k0 + 8*g + j > qg)          s0 = -3.0e38f;
          if (k0 + 8*g + 4 + j > qg)      s1 = -3.0e38f;
          if (k0 + 32 + 8*g + j > qg)     s2 = -3.0e38f;
          if (k0 + 32 + 8*g + 4 + j > qg) s3 = -3.0e38f;
        }
        p0[j] = fast_exp2(s0);
        p1[j] = fast_exp2(s1);
        p2[j] = fast_exp2(s2);
        p3[j] = fast_exp2(s3);
      }
      bf16x8 pfa, pfb;
      #pragma unroll
      for (int j = 0; j < 4; ++j) {
        pfa[j] = (bf16)p0[j]; pfa[4 + j] = (bf16)p1[j];
        pfb[j] = (bf16)p2[j]; pfb[4 + j] = (bf16)p3[j];
      }
      __builtin_amdgcn_s_setprio(1);
      #pragma unroll
      for (int c = 0; c < 4; ++c) {
        bf16x8 vfa = *(const bf16x8*)(Vb + oV[c]);
        bf16x8 vfb = *(const bf16x8*)(Vb + 2048 + oV[c]);
        ov[c] = mfma32(pfa, vfa, ov[c]);
        ov[c] = mfma32(pfb, vfb, ov[c]);
      }
      lacc = mfma32(pfa, onesf, lacc);
      lacc = mfma32(pfb, onesf, lacc);
      __builtin_amdgcn_s_setprio(0);
      __syncthreads();
      cur ^= 1;
    }
    #pragma unroll
    for (int j = 0; j < 4; ++j) {
      const float inv = 1.f / lacc[j];    // lacc[j] = l for q-row q0+4g+j
      const int row = b*SS + q0 + 4*g + j;
      #pragma unroll
      for (int c = 0; c < 4; ++c)
        ctx[(size_t)row * DD + h*HDIM + c*16 + r] = (bf16)(ov[c][j] * inv);
    }
  }
}

// ---------------- LayerNorm(a + sum(4 bf16 partials) + colbias) * g + b ----------------
template<int WRITEB>
__global__ __launch_bounds__(256)
void ln_bf4_kernel(const float* __restrict__ a, P4 part, const float* __restrict__ cb,
                   const float* __restrict__ gam, const float* __restrict__ bet,
                   float* __restrict__ outf, bf16* __restrict__ outb) {
  const int row = blockIdx.x;
  const int tid = threadIdx.x;
  const size_t base = (size_t)row * DD + tid * 4;
  float4 va = *(const float4*)(a + base);
  bf16x4 u0 = *(const bf16x4*)(part.p[0] + base);
  bf16x4 u1 = *(const bf16x4*)(part.p[1] + base);
  bf16x4 u2 = *(const bf16x4*)(part.p[2] + base);
  bf16x4 u3 = *(const bf16x4*)(part.p[3] + base);
  float4 vb4 = *(const float4*)(cb + tid * 4);
  float x0 = va.x + ((float)u0[0] + (float)u1[0]) + ((float)u2[0] + (float)u3[0]) + vb4.x;
  float x1 = va.y + ((float)u0[1] + (float)u1[1]) + ((float)u2[1] + (float)u3[1]) + vb4.y;
  float x2 = va.z + ((float)u0[2] + (float)u1[2]) + ((float)u2[2] + (float)u3[2]) + vb4.z;
  float x3 = va.w + ((float)u0[3] + (float)u1[3]) + ((float)u2[3] + (float)u3[3]) + vb4.w;
  float s  = x0 + x1 + x2 + x3;
  float s2 = x0*x0 + x1*x1 + x2*x2 + x3*x3;
  #pragma unroll
  for (int off = 32; off > 0; off >>= 1) {
    s  += __shfl_xor(s,  off);
    s2 += __shfl_xor(s2, off);
  }
  __shared__ float red[8];
  const int wv = tid >> 6;
  if ((tid & 63) == 0) { red[wv] = s; red[wv + 4] = s2; }
  __syncthreads();
  s  = red[0] + red[1] + red[2] + red[3];
  s2 = red[4] + red[5] + red[6] + red[7];
  const float mu  = s * (1.f / DD);
  const float var = s2 * (1.f / DD) - mu * mu;
  const float rs  = rsqrtf(var + 1e-5f);
  float4 vg = *(const float4*)(gam + tid * 4);
  float4 vb = *(const float4*)(bet + tid * 4);
  float y0 = (x0 - mu) * rs * vg.x + vb.x;
  float y1 = (x1 - mu) * rs * vg.y + vb.y;
  float y2 = (x2 - mu) * rs * vg.z + vb.z;
  float y3 = (x3 - mu) * rs * vg.w + vb.w;
  float4 yo; yo.x = y0; yo.y = y1; yo.z = y2; yo.w = y3;
  *(float4*)(outf + base) = yo;
  if (WRITEB) {
    bf16x4 ob;
    ob[0] = (bf16)y0; ob[1] = (bf16)y1; ob[2] = (bf16)y2; ob[3] = (bf16)y3;
    *(bf16x4*)(outb + base) = ob;
  }
}

extern "C" void kernel_launch(void* const* d_in, const int* in_sizes, int n_in,
                              void* d_out, int out_size, void* d_ws, size_t ws_size,
                              hipStream_t stream) {
  const float* src  = (const float*)d_in[0];
  const float* Wq   = (const float*)d_in[2];
  const float* bq   = (const float*)d_in[3];
  const float* Wk   = (const float*)d_in[4];
  const float* bk   = (const float*)d_in[5];
  const float* Wv   = (const float*)d_in[6];
  const float* bv   = (const float*)d_in[7];
  const float* Wo   = (const float*)d_in[8];
  const float* bo   = (const float*)d_in[9];
  const float* W1   = (const float*)d_in[10];
  const float* b1   = (const float*)d_in[11];
  const float* W2   = (const float*)d_in[12];
  const float* b2   = (const float*)d_in[13];
  const float* ln1g = (const float*)d_in[14];
  const float* ln1b = (const float*)d_in[15];
  const float* ln2g = (const float*)d_in[16];
  const float* ln2b = (const float*)d_in[17];

  char* ws = (char*)d_ws;
  const size_t MB = 1024 * 1024;
  bf16* wqkvt = (bf16*)(ws + 0 * MB);    // 6MB (dead after QKV)
  bf16* wot   = (bf16*)(ws + 6 * MB);    // 2MB (dead after Wo)
  bf16* w1t   = (bf16*)(ws + 8 * MB);    // 8MB (dead after FF1)
  bf16* w2t   = (bf16*)(ws + 16 * MB);   // 8MB (live through FF2)
  bf16* bsrc  = (bf16*)(ws + 24 * MB);   // 8MB; reused as xb (dead after FF1)
  bf16* xb    = bsrc;
  bf16* qkv   = (bf16*)(ws + 32 * MB);   // 24MB (dead after attn)
  bf16* vt    = (bf16*)(ws + 56 * MB);   // 8MB (dead after attn)
  bf16* ctx   = (bf16*)(ws + 64 * MB);   // 8MB (dead after Wo)
  bf16* ff1   = qkv;                     // [4096][4096] = 32MB, reuses qkv+vt
  float* xf   = (float*)(ws + 72 * MB);  // 16MB (live to LN2)
  float* bqkv = (float*)(ws + 88 * MB);  // 12KB
  float* outp = (float*)d_out;

  // Wo bf16 partials over dead qkv+vt region [32,64)
  P4 wop;
  wop.p[0] = (bf16*)(ws + 32 * MB);
  wop.p[1] = (bf16*)(ws + 40 * MB);
  wop.p[2] = (bf16*)(ws + 48 * MB);
  wop.p[3] = (bf16*)(ws + 56 * MB);
  // FF2 bf16 partials over regions dead at FF2 time
  P4 fp;
  fp.p[0] = (bf16*)(ws + 0 * MB);        // dead wqkvt(+wot)
  fp.p[1] = (bf16*)(ws + 8 * MB);        // dead w1t
  fp.p[2] = (bf16*)(ws + 24 * MB);       // dead xb
  fp.p[3] = (bf16*)(ws + 64 * MB);       // dead ctx

  // conversions
  cvt_bf16_kernel<<<(MR * DD) / 1024, 256, 0, stream>>>(src, bsrc, MR * DD);
  TP4 tp;
  tp.src[0] = Wq; tp.dst[0] = wqkvt;              tp.scale[0] = 0.18033688f; // 0.125*log2e
  tp.src[1] = Wk; tp.dst[1] = wqkvt + 1024*1024;  tp.scale[1] = 1.f;
  tp.src[2] = Wv; tp.dst[2] = wqkvt + 2048*1024;  tp.scale[2] = 1.f;
  tp.src[3] = Wo; tp.dst[3] = wot;                tp.scale[3] = 1.f;
  transpose_w4_kernel<<<dim3(32, 32, 4), 256, 0, stream>>>(tp);
  transpose_w_kernel<<<dim3(128, 32), 256, 0, stream>>>(W1, w1t, DD, FFD);
  transpose_w_kernel<<<dim3(32, 128), 256, 0, stream>>>(W2, w2t, FFD, DD);
  concat_bias_kernel<<<12, 256, 0, stream>>>(bq, bk, bv, bqkv);

  // fused QKV projection: 128x256 tiles, 384 blocks (1.5/CU)
  gemm_h<1, 0, 1><<<dim3(QKVLD / 256, MR / 128), 512, 0, stream>>>(bsrc, wqkvt, bqkv, qkv, P4{}, QKVLD, DD);
  transpose_v_kernel<<<dim3(SS / 32, HDIM / 32, BB * HH), 256, 0, stream>>>(qkv + 2048, vt);

  // attention (Q at col 0, K at col 1024 of qkv); 512 blocks, pair of tiles each
  attn_kernel<<<dim3(16, BB * HH), 256, 0, stream>>>(qkv, qkv + 1024, vt, ctx);

  // output projection: gemm_h split-K=4, 512 blocks (2/CU); reduce+bias in LN1
  gemm_h<0, 0, 4><<<dim3(DD / 256, MR / 128, 4), 512, 0, stream>>>(ctx, wot, nullptr, nullptr, wop, DD, DD);
  ln_bf4_kernel<1><<<MR, 256, 0, stream>>>(src, wop, bo, ln1g, ln1b, xf, xb);

  // FFN: FF1 128x256 tiles, 512 blocks (2/CU); FF2 gemm_h split-K=4
  gemm_h<1, 1, 1><<<dim3(FFD / 256, MR / 128), 512, 0, stream>>>(xb, w1t, b1, ff1, P4{}, FFD, DD);
  gemm_h<0, 0, 4><<<dim3(DD / 256, MR / 128, 4), 512, 0, stream>>>(ff1, w2t, nullptr, nullptr, fp, DD, FFD);
  ln_bf4_kernel<0><<<MR, 256, 0, stream>>>(xf, fp, b2, ln2g, ln2b, outp, nullptr);
}

// Round 19
// 215.123 us; speedup vs baseline: 1.0218x; 1.0218x over previous
//
#include <hip/hip_runtime.h>

#define SS 2048
#define DD 1024
#define HH 16
#define HDIM 64
#define BB 2
#define FFD 4096
#define MR (BB*SS)   // 4096 rows
#define QKVLD 3072   // fused qkv row stride

typedef __bf16 bf16;
typedef __bf16 bf16x4 __attribute__((ext_vector_type(4)));
typedef __bf16 bf16x8 __attribute__((ext_vector_type(8)));
typedef float f32x4 __attribute__((ext_vector_type(4)));

struct P4 { bf16* p[4]; };
struct TP4 { const float* src[4]; bf16* dst[4]; float scale[4]; };

__device__ inline f32x4 mfma32(bf16x8 a, bf16x8 b, f32x4 c) {
  return __builtin_amdgcn_mfma_f32_16x16x32_bf16(a, b, c, 0, 0, 0);
}

__device__ inline void gload_lds16(const void* g, void* l) {
  __builtin_amdgcn_global_load_lds(
      (const __attribute__((address_space(1))) void*)g,
      (__attribute__((address_space(3))) void*)l, 16, 0, 0);
}

// raw v_exp_f32 (2^x) — no libm denormal fixup (exp2f regressed R9; confirmed R10)
#if defined(__has_builtin)
#if __has_builtin(__builtin_amdgcn_exp2f)
#define HAVE_EXP2_BUILTIN 1
#endif
#endif
__device__ inline float fast_exp2(float x) {
#ifdef HAVE_EXP2_BUILTIN
  return __builtin_amdgcn_exp2f(x);
#else
  float r; asm("v_exp_f32 %0, %1" : "=v"(r) : "v"(x)); return r;
#endif
}

// ---------------- fp32 -> bf16 elementwise ----------------
__global__ __launch_bounds__(256)
void cvt_bf16_kernel(const float* __restrict__ in, bf16* __restrict__ out, int n) {
  int i = (blockIdx.x * 256 + threadIdx.x) * 4;
  if (i >= n) return;
  float4 v = *(const float4*)(in + i);
  bf16x4 o;
  o[0] = (bf16)v.x; o[1] = (bf16)v.y; o[2] = (bf16)v.z; o[3] = (bf16)v.w;
  *(bf16x4*)(out + i) = o;
}

// ---------------- concat bias qkv (bq pre-scaled by 0.125*log2e) ----------------
__global__ __launch_bounds__(256)
void concat_bias_kernel(const float* __restrict__ bq, const float* __restrict__ bk,
                        const float* __restrict__ bv, float* __restrict__ out) {
  int i = blockIdx.x * 256 + threadIdx.x;
  const float K2 = 0.18033688f;
  out[i] = i < 1024 ? bq[i] * K2 : (i < 2048 ? bk[i - 1024] : bv[i - 2048]);
}

// ---- 4x fused W [1024,1024] fp32 -> Wt bf16, optional per-matrix scale ----
__global__ __launch_bounds__(256)
void transpose_w4_kernel(TP4 t) {
  __shared__ float tl[32][33];
  const float* W = t.src[blockIdx.z];
  bf16* Wt = t.dst[blockIdx.z];
  const float sc = t.scale[blockIdx.z];
  int tx = threadIdx.x & 31, ty = threadIdx.x >> 5;  // 32 x 8
  int n0 = blockIdx.x * 32, k0 = blockIdx.y * 32;
  #pragma unroll
  for (int i = 0; i < 4; ++i)
    tl[ty + i*8][tx] = W[(size_t)(k0 + ty + i*8) * DD + n0 + tx];
  __syncthreads();
  #pragma unroll
  for (int i = 0; i < 4; ++i)
    Wt[(size_t)(n0 + ty + i*8) * DD + k0 + tx] = (bf16)(tl[tx][ty + i*8] * sc);
}

// ---------------- W [K,N] fp32 -> Wt [N,K] bf16 (W1/W2) ----------------
__global__ __launch_bounds__(256)
void transpose_w_kernel(const float* __restrict__ W, bf16* __restrict__ Wt,
                        int K, int N) {
  __shared__ float t[32][33];
  int tx = threadIdx.x & 31, ty = threadIdx.x >> 5;  // 32 x 8
  int n0 = blockIdx.x * 32, k0 = blockIdx.y * 32;
  #pragma unroll
  for (int i = 0; i < 4; ++i)
    t[ty + i*8][tx] = W[(size_t)(k0 + ty + i*8) * N + n0 + tx];
  __syncthreads();
  #pragma unroll
  for (int i = 0; i < 4; ++i)
    Wt[(size_t)(n0 + ty + i*8) * K + k0 + tx] = (bf16)t[tx][ty + i*8];
}

// ---------------- V (cols of qkv2d) -> Vt [B,H,HD,S] bf16 ----------------
__global__ __launch_bounds__(256)
void transpose_v_kernel(const bf16* __restrict__ V2d, bf16* __restrict__ Vt) {
  __shared__ bf16 t[32][33];
  int tx = threadIdx.x & 31, ty = threadIdx.x >> 5;
  int s0 = blockIdx.x * 32, d0 = blockIdx.y * 32;
  int bh = blockIdx.z;
  int b = bh >> 4, h = bh & 15;
  #pragma unroll
  for (int i = 0; i < 4; ++i)
    t[ty + i*8][tx] = V2d[(size_t)(b*SS + s0 + ty + i*8) * QKVLD + h*HDIM + d0 + tx];
  __syncthreads();
  #pragma unroll
  for (int i = 0; i < 4; ++i)
    Vt[((size_t)bh*HDIM + d0 + ty + i*8) * SS + s0 + tx] = t[tx][ty + i*8];
}

// ======== gemm_h: 128(M)x256(N) tile, BK=32, 8 waves, 48KB LDS dbuf ========
template<int OUT_BF16, int RELU, int SPLITK>
__global__ __launch_bounds__(512)
void gemm_h(const bf16* __restrict__ A, const bf16* __restrict__ Bt,
            const float* __restrict__ bias, void* __restrict__ Cout,
            P4 part, int Ndim, int Kdim) {
  __shared__ bf16 Asm[2][128 * 32];   // 8KB x2
  __shared__ bf16 Bsm[2][256 * 32];   // 16KB x2 => 48KB
  const int gx = gridDim.x, gy = gridDim.y;
  const int gxy = gx * gy;
  const int nwg = gxy * gridDim.z;
  const int lin = (blockIdx.z * gy + blockIdx.y) * gx + blockIdx.x;
  const int swz = (lin & 7) * (nwg >> 3) + (lin >> 3);
  int bz = 0, rem = swz;
  if (SPLITK > 1) { bz = swz / gxy; rem = swz - bz * gxy; }
  const int by = rem / gx, bx = rem - by * gx;
  const int m0 = by * 128, n0 = bx * 256;
  const int tid = threadIdx.x;
  const int wave = tid >> 6, lane = tid & 63;
  const int g = lane >> 4, r = lane & 15;
  const int wr = wave >> 2, wn = wave & 3;   // 2M x 4N -> per-wave 64x64
  const int kstart = bz * (Kdim / SPLITK);

  const int lrow = lane >> 2;                 // 0..15
  const int lslot = (lane & 3) ^ (lrow & 3);  // pre-swizzled global slot
  const bf16* Ag = A + (size_t)(m0 + wave * 16 + lrow) * Kdim + kstart + lslot * 8;
  const bf16* Bg0 = Bt + (size_t)(n0 + wave * 32 + lrow) * Kdim + kstart + lslot * 8;
  const bf16* Bg1 = Bg0 + (size_t)16 * Kdim;

  f32x4 acc[4][4] = {};
  const int NT = (Kdim / SPLITK) >> 5;

  auto stage = [&](int t) {
    const int kb = t << 5;
    bf16* Ad = Asm[t & 1] + wave * 512;          // wave's 16 rows x 32
    bf16* Bd = Bsm[t & 1] + wave * 1024;         // wave's 32 rows x 32
    gload_lds16(Ag + kb, Ad);
    gload_lds16(Bg0 + kb, Bd);
    gload_lds16(Bg1 + kb, Bd + 512);
  };

  stage(0);
  __syncthreads();

  for (int t = 0; t < NT; ++t) {
    const bf16* Ab = Asm[t & 1];
    const bf16* Bb = Bsm[t & 1];
    bf16x8 af[4], bfr[4];
    #pragma unroll
    for (int i = 0; i < 4; ++i) {
      const int row = wr * 64 + i * 16 + r;
      af[i] = *(const bf16x8*)(Ab + row * 32 + ((g ^ (r & 3)) * 8));
    }
    #pragma unroll
    for (int i = 0; i < 4; ++i) {
      const int rowb = wn * 64 + i * 16 + r;
      bfr[i] = *(const bf16x8*)(Bb + rowb * 32 + ((g ^ (r & 3)) * 8));
    }
    if (t + 1 < NT) stage(t + 1);
    __builtin_amdgcn_s_setprio(1);
    #pragma unroll
    for (int i = 0; i < 4; ++i)
      #pragma unroll
      for (int jn = 0; jn < 4; ++jn)
        acc[i][jn] = mfma32(af[i], bfr[jn], acc[i][jn]);
    __builtin_amdgcn_s_setprio(0);
    __syncthreads();
  }

  #pragma unroll
  for (int mi = 0; mi < 4; ++mi) {
    #pragma unroll
    for (int ni = 0; ni < 4; ++ni) {
      const int col = n0 + wn * 64 + ni * 16 + r;
      const float bv = (SPLITK > 1) ? 0.f : bias[col];
      #pragma unroll
      for (int jj = 0; jj < 4; ++jj) {
        const int row = m0 + wr * 64 + mi * 16 + g * 4 + jj;
        float v = acc[mi][ni][jj] + bv;
        if (RELU) v = fmaxf(v, 0.f);
        if (SPLITK > 1) part.p[bz][(size_t)row * Ndim + col] = (bf16)v;
        else if (OUT_BF16) ((bf16*)Cout)[(size_t)row * Ndim + col] = (bf16)v;
        else               ((float*)Cout)[(size_t)row * Ndim + col] = v;
      }
    }
  }
}

// ======== 256x256 GEMM (R13-proven): min-LDS-read 2-phase, counted vmcnt ========
// Used for Wo/FF2 split-K=4 (R17 measured-best for those shapes).
template<int OUT_BF16, int RELU, int SPLITK>
__global__ __launch_bounds__(512)
void gemm256(const bf16* __restrict__ A, const bf16* __restrict__ Bt,
             const float* __restrict__ bias, void* __restrict__ Cout,
             P4 part, int Ndim, int Kdim) {
  __shared__ bf16 Asm[3][256 * 64];   // 96KB
  __shared__ bf16 Bsm[2][256 * 64];   // 64KB
  const int gx = gridDim.x, gy = gridDim.y;
  const int gxy = gx * gy;
  const int nwg = gxy * gridDim.z;
  const int lin = (blockIdx.z * gy + blockIdx.y) * gx + blockIdx.x;
  const int swz = (lin & 7) * (nwg >> 3) + (lin >> 3);
  int bz = 0, rem = swz;
  if (SPLITK > 1) { bz = swz / gxy; rem = swz - bz * gxy; }
  const int by = rem / gx, bx = rem - by * gx;
  const int m0 = by * 256, n0 = bx * 256;
  const int tid = threadIdx.x;
  const int wave = tid >> 6, lane = tid & 63;
  const int g = lane >> 4, r = lane & 15;
  const int wr = wave >> 2, wn = wave & 3;
  const int kstart = bz * (Kdim / SPLITK);

  const int srow = wave * 8 + (lane >> 3);
  const int skslot = (lane & 7) ^ (lane >> 3);
  const bf16* Ag = A + (size_t)(m0 + srow) * Kdim + kstart + skslot * 8;
  const bf16* Bg = Bt + (size_t)(n0 + srow) * Kdim + kstart + skslot * 8;

  f32x4 acc[8][4] = {};
  const int NT = (Kdim / SPLITK) >> 6;

  auto stageA = [&](int t) {
    if (t >= NT) return;
    const int kb = t << 6;
    bf16* Ad = Asm[t % 3];
    #pragma unroll
    for (int j = 0; j < 4; ++j)
      gload_lds16(Ag + (size_t)j * 64 * Kdim + kb, Ad + (j * 64 + wave * 8) * 64);
  };
  auto stageB = [&](int t) {
    if (t >= NT) return;
    const int kb = t << 6;
    bf16* Bd = Bsm[t & 1];
    #pragma unroll
    for (int j = 0; j < 4; ++j)
      gload_lds16(Bg + (size_t)j * 64 * Kdim + kb, Bd + (j * 64 + wave * 8) * 64);
  };

  stageA(0);
  stageB(0);
  stageA(1);
  asm volatile("s_waitcnt vmcnt(4)" ::: "memory");
  asm volatile("s_barrier" ::: "memory");

  for (int t = 0; t < NT; ++t) {
    const bf16* Ab = Asm[t % 3];
    const bf16* Bb = Bsm[t & 1];
    bf16x8 bfr[4][2];
    #pragma unroll
    for (int i = 0; i < 4; ++i) {
      const int rowb = wn * 64 + i * 16 + r;
      #pragma unroll
      for (int kk = 0; kk < 2; ++kk)
        bfr[i][kk] = *(const bf16x8*)(Bb + rowb * 64 + (((kk * 4 + g) ^ (r & 7)) * 8));
    }
    #pragma unroll
    for (int ph = 0; ph < 2; ++ph) {
      bf16x8 af[4][2];
      #pragma unroll
      for (int i = 0; i < 4; ++i) {
        const int row = wr * 128 + (ph * 4 + i) * 16 + r;
        #pragma unroll
        for (int kk = 0; kk < 2; ++kk)
          af[i][kk] = *(const bf16x8*)(Ab + row * 64 + (((kk * 4 + g) ^ (r & 7)) * 8));
      }
      if (ph == 0) stageB(t + 1);
      if (ph == 1) stageA(t + 2);
      asm volatile("s_barrier" ::: "memory");
      __builtin_amdgcn_s_setprio(1);
      #pragma unroll
      for (int i = 0; i < 4; ++i)
        #pragma unroll
        for (int jn = 0; jn < 4; ++jn)
          #pragma unroll
          for (int kk = 0; kk < 2; ++kk)
            acc[ph * 4 + i][jn] = mfma32(af[i][kk], bfr[jn][kk], acc[ph * 4 + i][jn]);
      __builtin_amdgcn_s_setprio(0);
      asm volatile("s_barrier" ::: "memory");
    }
    if (t + 1 < NT) {
      if (t + 2 < NT) asm volatile("s_waitcnt vmcnt(4)" ::: "memory");
      else            asm volatile("s_waitcnt vmcnt(0)" ::: "memory");
      asm volatile("s_barrier" ::: "memory");
    }
  }

  #pragma unroll
  for (int mi = 0; mi < 8; ++mi) {
    #pragma unroll
    for (int ni = 0; ni < 4; ++ni) {
      const int col = n0 + wn * 64 + ni * 16 + r;
      const float bv = (SPLITK > 1) ? 0.f : bias[col];
      #pragma unroll
      for (int jj = 0; jj < 4; ++jj) {
        const int row = m0 + wr * 128 + mi * 16 + g * 4 + jj;
        float v = acc[mi][ni][jj] + bv;
        if (RELU) v = fmaxf(v, 0.f);
        if (SPLITK > 1) part.p[bz][(size_t)row * Ndim + col] = (bf16)v;
        else if (OUT_BF16) ((bf16*)Cout)[(size_t)row * Ndim + col] = (bf16)v;
        else               ((float*)Cout)[(size_t)row * Ndim + col] = v;
      }
    }
  }
}

// ---------------- flash attention v8: KVBLK=128 ----------------
// Same per-element math as v7 (Q pre-scaled log2 domain, no-max softmax,
// lacc via ones-MFMA, (row>>1)&3 swizzle both-sides). KVBLK doubled to 128:
// two 64-krow sub-groups per step (sub1 at +4096 elem offset), halving the
// per-step barrier/vmcnt-drain fixed cost. Even tiles overshoot the diagonal
// by 64 fully-masked krows (exp2(-3e38)=0, exact). Pairing stays uniform:
// steps(p)+steps(31-p) = 17 for all p. LDS 64KB/block -> still 2 blocks/CU.
__global__ __launch_bounds__(256)
void attn_kernel(const bf16* __restrict__ Q2d, const bf16* __restrict__ K2d,
                 const bf16* __restrict__ Vt, bf16* __restrict__ ctx) {
  __shared__ bf16 Ks[2 * 8192];   // 2 bufs x [2 krow-groups][2 halves][64][32]
  __shared__ bf16 Vs[2 * 8192];   // 2 bufs x [4 col-quarters][64][32]
  const int tid = threadIdx.x;
  const int wave = tid >> 6;
  const int lane = tid & 63;
  const int g = lane >> 4, r = lane & 15;
  const int lin = blockIdx.y * gridDim.x + blockIdx.x;   // 0..511
  const int swz = (lin & 7) * 64 + (lin >> 3);
  const int p = swz & 15;            // pair index 0..15
  const int bh = swz >> 4;           // 0..31
  const int b = bh >> 4, h = bh & 15;

  const int strow = wave * 16 + (lane >> 2);              // 0..63
  const int lslot = (lane & 3) ^ ((lane >> 3) & 3);       // pre-swizzled global slot
  const bf16* srcK0  = K2d + (size_t)(b*SS + strow) * QKVLD + h*HDIM + lslot * 8;
  const bf16* srcK1  = srcK0 + 32;
  const bf16* srcKh0 = srcK0 + (size_t)64 * QKVLD;        // krows 64..127 of step
  const bf16* srcKh1 = srcK1 + (size_t)64 * QKVLD;
  const bf16* srcV0  = Vt + ((size_t)bh*HDIM + strow) * SS + lslot * 8;
  const bf16* srcV1  = srcV0 + 32;

  auto sw = [](int row, int s) { return row * 32 + ((s ^ ((row >> 1) & 3)) * 8); };

  const int kr0 = 8 * (r >> 2) + (r & 3);      // permuted K row for S^T frag
  const int oKa0 = sw(kr0,      g), oKb0 = 2048 + oKa0;
  const int oKa1 = sw(kr0 +  4, g), oKb1 = 2048 + oKa1;
  const int oKa2 = sw(kr0 + 32, g), oKb2 = 2048 + oKa2;
  const int oKa3 = sw(kr0 + 36, g), oKb3 = 2048 + oKa3;
  int oV[4];
  #pragma unroll
  for (int c = 0; c < 4; ++c) oV[c] = sw(c * 16 + r, g);

  bf16x8 onesf;
  #pragma unroll
  for (int j = 0; j < 8; ++j) onesf[j] = (bf16)1.0f;

  #pragma unroll
  for (int tt = 0; tt < 2; ++tt) {
    const int tile = tt ? (31 - p) : p;
    const int q0 = tile * 64 + wave * 16;
    const int qg = q0 + r;
    const bf16* qp = Q2d + (size_t)(b*SS + q0 + r) * QKVLD + h * HDIM;
    const bf16x8 qf0 = *(const bf16x8*)(qp + g * 8);
    const bf16x8 qf1 = *(const bf16x8*)(qp + 32 + g * 8);
    f32x4 ov[4] = {};
    f32x4 lacc = {};                // row-sum l via ones-column MFMA
    const int nst = (tile >> 1) + 1;   // 128-krow steps
    {
      bf16* kb = Ks + wave * 512;
      bf16* vb = Vs + wave * 512;
      gload_lds16(srcK0,  kb);
      gload_lds16(srcK1,  kb + 2048);
      gload_lds16(srcKh0, kb + 4096);
      gload_lds16(srcKh1, kb + 6144);
      gload_lds16(srcV0,      vb);
      gload_lds16(srcV1,      vb + 2048);
      gload_lds16(srcV0 + 64, vb + 4096);
      gload_lds16(srcV1 + 64, vb + 6144);
    }
    __syncthreads();
    int cur = 0;
    for (int st = 0; st < nst; ++st) {
      const int k0 = st * 128;
      if (st + 1 < nst) {
        const int kn = k0 + 128;
        bf16* kb = Ks + (cur ^ 1) * 8192 + wave * 512;
        bf16* vb = Vs + (cur ^ 1) * 8192 + wave * 512;
        gload_lds16(srcK0  + (size_t)kn * QKVLD, kb);
        gload_lds16(srcK1  + (size_t)kn * QKVLD, kb + 2048);
        gload_lds16(srcKh0 + (size_t)kn * QKVLD, kb + 4096);
        gload_lds16(srcKh1 + (size_t)kn * QKVLD, kb + 6144);
        gload_lds16(srcV0 + kn,      vb);
        gload_lds16(srcV1 + kn,      vb + 2048);
        gload_lds16(srcV0 + kn + 64, vb + 4096);
        gload_lds16(srcV1 + kn + 64, vb + 6144);
      }
      const bf16* Kb = Ks + cur * 8192;
      const bf16* Vb = Vs + cur * 8192;
      f32x4 c0 = {}, c1 = {}, c2 = {}, c3 = {};
      f32x4 c4 = {}, c5 = {}, c6 = {}, c7 = {};
      __builtin_amdgcn_s_setprio(1);
      c0 = mfma32(*(const bf16x8*)(Kb + oKa0), qf0, c0);
      c1 = mfma32(*(const bf16x8*)(Kb + oKa1), qf0, c1);
      c2 = mfma32(*(const bf16x8*)(Kb + oKa2), qf0, c2);
      c3 = mfma32(*(const bf16x8*)(Kb + oKa3), qf0, c3);
      c0 = mfma32(*(const bf16x8*)(Kb + oKb0), qf1, c0);
      c1 = mfma32(*(const bf16x8*)(Kb + oKb1), qf1, c1);
      c2 = mfma32(*(const bf16x8*)(Kb + oKb2), qf1, c2);
      c3 = mfma32(*(const bf16x8*)(Kb + oKb3), qf1, c3);
      c4 = mfma32(*(const bf16x8*)(Kb + 4096 + oKa0), qf0, c4);
      c5 = mfma32(*(const bf16x8*)(Kb + 4096 + oKa1), qf0, c5);
      c6 = mfma32(*(const bf16x8*)(Kb + 4096 + oKa2), qf0, c6);
      c7 = mfma32(*(const bf16x8*)(Kb + 4096 + oKa3), qf0, c7);
      c4 = mfma32(*(const bf16x8*)(Kb + 4096 + oKb0), qf1, c4);
      c5 = mfma32(*(const bf16x8*)(Kb + 4096 + oKb1), qf1, c5);
      c6 = mfma32(*(const bf16x8*)(Kb + 4096 + oKb2), qf1, c6);
      c7 = mfma32(*(const bf16x8*)(Kb + 4096 + oKb3), qf1, c7);
      __builtin_amdgcn_s_setprio(0);
      // scores in log2 domain; masked -> 0 via exp2(-3e38)
      float p0[4], p1[4], p2[4], p3[4], p4[4], p5[4], p6[4], p7[4];
      const bool need_mask = (k0 + 127 > qg);
      #pragma unroll
      for (int j = 0; j < 4; ++j) {
        float s0 = c0[j], s1 = c1[j], s2 = c2[j], s3 = c3[j];
        float s4 = c4[j], s5 = c5[j], s6 = c6[j], s7 = c7[j];
        if (need_mask) {
          if (k0 + 8*g + j > qg)           s0 = -3.0e38f;
          if (k0 + 8*g + 4 + j > qg)       s1 = -3.0e38f;
          if (k0 + 32 + 8*g + j > qg)      s2 = -3.0e38f;
          if (k0 + 32 + 8*g + 4 + j > qg)  s3 = -3.0e38f;
          if (k0 + 64 + 8*g + j > qg)      s4 = -3.0e38f;
          if (k0 + 64 + 8*g + 4 + j > qg)  s5 = -3.0e38f;
          if (k0 + 96 + 8*g + j > qg)      s6 = -3.0e38f;
          if (k0 + 96 + 8*g + 4 + j > qg)  s7 = -3.0e38f;
        }
        p0[j] = fast_exp2(s0);
        p1[j] = fast_exp2(s1);
        p2[j] = fast_exp2(s2);
        p3[j] = fast_exp2(s3);
        p4[j] = fast_exp2(s4);
        p5[j] = fast_exp2(s5);
        p6[j] = fast_exp2(s6);
        p7[j] = fast_exp2(s7);
      }
      bf16x8 pfa, pfb, pfc, pfd;
      #pragma unroll
      for (int j = 0; j < 4; ++j) {
        pfa[j] = (bf16)p0[j]; pfa[4 + j] = (bf16)p1[j];
        pfb[j] = (bf16)p2[j]; pfb[4 + j] = (bf16)p3[j];
        pfc[j] = (bf16)p4[j]; pfc[4 + j] = (bf16)p5[j];
        pfd[j] = (bf16)p6[j]; pfd[4 + j] = (bf16)p7[j];
      }
      __builtin_amdgcn_s_setprio(1);
      #pragma unroll
      for (int c = 0; c < 4; ++c) {
        bf16x8 vfa = *(const bf16x8*)(Vb + oV[c]);
        bf16x8 vfb = *(const bf16x8*)(Vb + 2048 + oV[c]);
        bf16x8 vfc = *(const bf16x8*)(Vb + 4096 + oV[c]);
        bf16x8 vfd = *(const bf16x8*)(Vb + 6144 + oV[c]);
        ov[c] = mfma32(pfa, vfa, ov[c]);
        ov[c] = mfma32(pfb, vfb, ov[c]);
        ov[c] = mfma32(pfc, vfc, ov[c]);
        ov[c] = mfma32(pfd, vfd, ov[c]);
      }
      lacc = mfma32(pfa, onesf, lacc);
      lacc = mfma32(pfb, onesf, lacc);
      lacc = mfma32(pfc, onesf, lacc);
      lacc = mfma32(pfd, onesf, lacc);
      __builtin_amdgcn_s_setprio(0);
      __syncthreads();
      cur ^= 1;
    }
    #pragma unroll
    for (int j = 0; j < 4; ++j) {
      const float inv = 1.f / lacc[j];    // lacc[j] = l for q-row q0+4g+j
      const int row = b*SS + q0 + 4*g + j;
      #pragma unroll
      for (int c = 0; c < 4; ++c)
        ctx[(size_t)row * DD + h*HDIM + c*16 + r] = (bf16)(ov[c][j] * inv);
    }
  }
}

// ---------------- LayerNorm(a + sum(4 bf16 partials) + colbias) * g + b ----------------
template<int WRITEB>
__global__ __launch_bounds__(256)
void ln_bf4_kernel(const float* __restrict__ a, P4 part, const float* __restrict__ cb,
                   const float* __restrict__ gam, const float* __restrict__ bet,
                   float* __restrict__ outf, bf16* __restrict__ outb) {
  const int row = blockIdx.x;
  const int tid = threadIdx.x;
  const size_t base = (size_t)row * DD + tid * 4;
  float4 va = *(const float4*)(a + base);
  bf16x4 u0 = *(const bf16x4*)(part.p[0] + base);
  bf16x4 u1 = *(const bf16x4*)(part.p[1] + base);
  bf16x4 u2 = *(const bf16x4*)(part.p[2] + base);
  bf16x4 u3 = *(const bf16x4*)(part.p[3] + base);
  float4 vb4 = *(const float4*)(cb + tid * 4);
  float x0 = va.x + ((float)u0[0] + (float)u1[0]) + ((float)u2[0] + (float)u3[0]) + vb4.x;
  float x1 = va.y + ((float)u0[1] + (float)u1[1]) + ((float)u2[1] + (float)u3[1]) + vb4.y;
  float x2 = va.z + ((float)u0[2] + (float)u1[2]) + ((float)u2[2] + (float)u3[2]) + vb4.z;
  float x3 = va.w + ((float)u0[3] + (float)u1[3]) + ((float)u2[3] + (float)u3[3]) + vb4.w;
  float s  = x0 + x1 + x2 + x3;
  float s2 = x0*x0 + x1*x1 + x2*x2 + x3*x3;
  #pragma unroll
  for (int off = 32; off > 0; off >>= 1) {
    s  += __shfl_xor(s,  off);
    s2 += __shfl_xor(s2, off);
  }
  __shared__ float red[8];
  const int wv = tid >> 6;
  if ((tid & 63) == 0) { red[wv] = s; red[wv + 4] = s2; }
  __syncthreads();
  s  = red[0] + red[1] + red[2] + red[3];
  s2 = red[4] + red[5] + red[6] + red[7];
  const float mu  = s * (1.f / DD);
  const float var = s2 * (1.f / DD) - mu * mu;
  const float rs  = rsqrtf(var + 1e-5f);
  float4 vg = *(const float4*)(gam + tid * 4);
  float4 vb = *(const float4*)(bet + tid * 4);
  float y0 = (x0 - mu) * rs * vg.x + vb.x;
  float y1 = (x1 - mu) * rs * vg.y + vb.y;
  float y2 = (x2 - mu) * rs * vg.z + vb.z;
  float y3 = (x3 - mu) * rs * vg.w + vb.w;
  float4 yo; yo.x = y0; yo.y = y1; yo.z = y2; yo.w = y3;
  *(float4*)(outf + base) = yo;
  if (WRITEB) {
    bf16x4 ob;
    ob[0] = (bf16)y0; ob[1] = (bf16)y1; ob[2] = (bf16)y2; ob[3] = (bf16)y3;
    *(bf16x4*)(outb + base) = ob;
  }
}

extern "C" void kernel_launch(void* const* d_in, const int* in_sizes, int n_in,
                              void* d_out, int out_size, void* d_ws, size_t ws_size,
                              hipStream_t stream) {
  const float* src  = (const float*)d_in[0];
  const float* Wq   = (const float*)d_in[2];
  const float* bq   = (const float*)d_in[3];
  const float* Wk   = (const float*)d_in[4];
  const float* bk   = (const float*)d_in[5];
  const float* Wv   = (const float*)d_in[6];
  const float* bv   = (const float*)d_in[7];
  const float* Wo   = (const float*)d_in[8];
  const float* bo   = (const float*)d_in[9];
  const float* W1   = (const float*)d_in[10];
  const float* b1   = (const float*)d_in[11];
  const float* W2   = (const float*)d_in[12];
  const float* b2   = (const float*)d_in[13];
  const float* ln1g = (const float*)d_in[14];
  const float* ln1b = (const float*)d_in[15];
  const float* ln2g = (const float*)d_in[16];
  const float* ln2b = (const float*)d_in[17];

  char* ws = (char*)d_ws;
  const size_t MB = 1024 * 1024;
  bf16* wqkvt = (bf16*)(ws + 0 * MB);    // 6MB (dead after QKV)
  bf16* wot   = (bf16*)(ws + 6 * MB);    // 2MB (dead after Wo)
  bf16* w1t   = (bf16*)(ws + 8 * MB);    // 8MB (dead after FF1)
  bf16* w2t   = (bf16*)(ws + 16 * MB);   // 8MB (live through FF2)
  bf16* bsrc  = (bf16*)(ws + 24 * MB);   // 8MB; reused as xb (dead after FF1)
  bf16* xb    = bsrc;
  bf16* qkv   = (bf16*)(ws + 32 * MB);   // 24MB (dead after attn)
  bf16* vt    = (bf16*)(ws + 56 * MB);   // 8MB (dead after attn)
  bf16* ctx   = (bf16*)(ws + 64 * MB);   // 8MB (dead after Wo)
  bf16* ff1   = qkv;                     // [4096][4096] = 32MB, reuses qkv+vt
  float* xf   = (float*)(ws + 72 * MB);  // 16MB (live to LN2)
  float* bqkv = (float*)(ws + 88 * MB);  // 12KB
  float* outp = (float*)d_out;

  // Wo bf16 partials over dead qkv+vt region [32,64)
  P4 wop;
  wop.p[0] = (bf16*)(ws + 32 * MB);
  wop.p[1] = (bf16*)(ws + 40 * MB);
  wop.p[2] = (bf16*)(ws + 48 * MB);
  wop.p[3] = (bf16*)(ws + 56 * MB);
  // FF2 bf16 partials over regions dead at FF2 time
  P4 fp;
  fp.p[0] = (bf16*)(ws + 0 * MB);        // dead wqkvt(+wot)
  fp.p[1] = (bf16*)(ws + 8 * MB);        // dead w1t
  fp.p[2] = (bf16*)(ws + 24 * MB);       // dead xb
  fp.p[3] = (bf16*)(ws + 64 * MB);       // dead ctx

  // conversions
  cvt_bf16_kernel<<<(MR * DD) / 1024, 256, 0, stream>>>(src, bsrc, MR * DD);
  TP4 tp;
  tp.src[0] = Wq; tp.dst[0] = wqkvt;              tp.scale[0] = 0.18033688f; // 0.125*log2e
  tp.src[1] = Wk; tp.dst[1] = wqkvt + 1024*1024;  tp.scale[1] = 1.f;
  tp.src[2] = Wv; tp.dst[2] = wqkvt + 2048*1024;  tp.scale[2] = 1.f;
  tp.src[3] = Wo; tp.dst[3] = wot;                tp.scale[3] = 1.f;
  transpose_w4_kernel<<<dim3(32, 32, 4), 256, 0, stream>>>(tp);
  transpose_w_kernel<<<dim3(128, 32), 256, 0, stream>>>(W1, w1t, DD, FFD);
  transpose_w_kernel<<<dim3(32, 128), 256, 0, stream>>>(W2, w2t, FFD, DD);
  concat_bias_kernel<<<12, 256, 0, stream>>>(bq, bk, bv, bqkv);

  // fused QKV projection: 128x256 tiles, 384 blocks (1.5/CU)
  gemm_h<1, 0, 1><<<dim3(QKVLD / 256, MR / 128), 512, 0, stream>>>(bsrc, wqkvt, bqkv, qkv, P4{}, QKVLD, DD);
  transpose_v_kernel<<<dim3(SS / 32, HDIM / 32, BB * HH), 256, 0, stream>>>(qkv + 2048, vt);

  // attention (Q at col 0, K at col 1024 of qkv); 512 blocks, pair of tiles each
  attn_kernel<<<dim3(16, BB * HH), 256, 0, stream>>>(qkv, qkv + 1024, vt, ctx);

  // output projection: gemm256 split-K=4 (R17 measured-best); reduce+bias in LN1
  gemm256<0, 0, 4><<<dim3(DD / 256, MR / 256, 4), 512, 0, stream>>>(ctx, wot, nullptr, nullptr, wop, DD, DD);
  ln_bf4_kernel<1><<<MR, 256, 0, stream>>>(src, wop, bo, ln1g, ln1b, xf, xb);

  // FFN: FF1 128x256 tiles, 512 blocks (2/CU); FF2 gemm256 split-K=4
  gemm_h<1, 1, 1><<<dim3(FFD / 256, MR / 128), 512, 0, stream>>>(xb, w1t, b1, ff1, P4{}, FFD, DD);
  gemm256<0, 0, 4><<<dim3(DD / 256, MR / 256, 4), 512, 0, stream>>>(ff1, w2t, nullptr, nullptr, fp, DD, FFD);
  ln_bf4_kernel<0><<<MR, 256, 0, stream>>>(xf, fp, b2, ln2g, ln2b, outp, nullptr);
}

// Round 20
// 213.781 us; speedup vs baseline: 1.0282x; 1.0063x over previous
//
#include <hip/hip_runtime.h>

#define SS 2048
#define DD 1024
#define HH 16
#define HDIM 64
#define BB 2
#define FFD 4096
#define MR (BB*SS)   // 4096 rows
#define QKVLD 3072   // fused qkv row stride

typedef __bf16 bf16;
typedef __bf16 bf16x4 __attribute__((ext_vector_type(4)));
typedef __bf16 bf16x8 __attribute__((ext_vector_type(8)));
typedef float f32x4 __attribute__((ext_vector_type(4)));

struct P4 { bf16* p[4]; };
struct TP4 { const float* src[4]; bf16* dst[4]; float scale[4]; };

__device__ inline f32x4 mfma32(bf16x8 a, bf16x8 b, f32x4 c) {
  return __builtin_amdgcn_mfma_f32_16x16x32_bf16(a, b, c, 0, 0, 0);
}

__device__ inline void gload_lds16(const void* g, void* l) {
  __builtin_amdgcn_global_load_lds(
      (const __attribute__((address_space(1))) void*)g,
      (__attribute__((address_space(3))) void*)l, 16, 0, 0);
}

// raw v_exp_f32 (2^x) — no libm denormal fixup (exp2f regressed R9; confirmed R10)
#if defined(__has_builtin)
#if __has_builtin(__builtin_amdgcn_exp2f)
#define HAVE_EXP2_BUILTIN 1
#endif
#endif
__device__ inline float fast_exp2(float x) {
#ifdef HAVE_EXP2_BUILTIN
  return __builtin_amdgcn_exp2f(x);
#else
  float r; asm("v_exp_f32 %0, %1" : "=v"(r) : "v"(x)); return r;
#endif
}

// ---------------- fp32 -> bf16 elementwise ----------------
__global__ __launch_bounds__(256)
void cvt_bf16_kernel(const float* __restrict__ in, bf16* __restrict__ out, int n) {
  int i = (blockIdx.x * 256 + threadIdx.x) * 4;
  if (i >= n) return;
  float4 v = *(const float4*)(in + i);
  bf16x4 o;
  o[0] = (bf16)v.x; o[1] = (bf16)v.y; o[2] = (bf16)v.z; o[3] = (bf16)v.w;
  *(bf16x4*)(out + i) = o;
}

// ---------------- concat bias qkv (bq pre-scaled by 0.125*log2e) ----------------
__global__ __launch_bounds__(256)
void concat_bias_kernel(const float* __restrict__ bq, const float* __restrict__ bk,
                        const float* __restrict__ bv, float* __restrict__ out) {
  int i = blockIdx.x * 256 + threadIdx.x;
  const float K2 = 0.18033688f;
  out[i] = i < 1024 ? bq[i] * K2 : (i < 2048 ? bk[i - 1024] : bv[i - 2048]);
}

// ---- 4x fused W [1024,1024] fp32 -> Wt bf16, optional per-matrix scale ----
__global__ __launch_bounds__(256)
void transpose_w4_kernel(TP4 t) {
  __shared__ float tl[32][33];
  const float* W = t.src[blockIdx.z];
  bf16* Wt = t.dst[blockIdx.z];
  const float sc = t.scale[blockIdx.z];
  int tx = threadIdx.x & 31, ty = threadIdx.x >> 5;  // 32 x 8
  int n0 = blockIdx.x * 32, k0 = blockIdx.y * 32;
  #pragma unroll
  for (int i = 0; i < 4; ++i)
    tl[ty + i*8][tx] = W[(size_t)(k0 + ty + i*8) * DD + n0 + tx];
  __syncthreads();
  #pragma unroll
  for (int i = 0; i < 4; ++i)
    Wt[(size_t)(n0 + ty + i*8) * DD + k0 + tx] = (bf16)(tl[tx][ty + i*8] * sc);
}

// ---------------- W [K,N] fp32 -> Wt [N,K] bf16 (W1/W2) ----------------
__global__ __launch_bounds__(256)
void transpose_w_kernel(const float* __restrict__ W, bf16* __restrict__ Wt,
                        int K, int N) {
  __shared__ float t[32][33];
  int tx = threadIdx.x & 31, ty = threadIdx.x >> 5;  // 32 x 8
  int n0 = blockIdx.x * 32, k0 = blockIdx.y * 32;
  #pragma unroll
  for (int i = 0; i < 4; ++i)
    t[ty + i*8][tx] = W[(size_t)(k0 + ty + i*8) * N + n0 + tx];
  __syncthreads();
  #pragma unroll
  for (int i = 0; i < 4; ++i)
    Wt[(size_t)(n0 + ty + i*8) * K + k0 + tx] = (bf16)t[tx][ty + i*8];
}

// ---------------- V (cols of qkv2d) -> Vt [B,H,HD,S] bf16 ----------------
__global__ __launch_bounds__(256)
void transpose_v_kernel(const bf16* __restrict__ V2d, bf16* __restrict__ Vt) {
  __shared__ bf16 t[32][33];
  int tx = threadIdx.x & 31, ty = threadIdx.x >> 5;
  int s0 = blockIdx.x * 32, d0 = blockIdx.y * 32;
  int bh = blockIdx.z;
  int b = bh >> 4, h = bh & 15;
  #pragma unroll
  for (int i = 0; i < 4; ++i)
    t[ty + i*8][tx] = V2d[(size_t)(b*SS + s0 + ty + i*8) * QKVLD + h*HDIM + d0 + tx];
  __syncthreads();
  #pragma unroll
  for (int i = 0; i < 4; ++i)
    Vt[((size_t)bh*HDIM + d0 + ty + i*8) * SS + s0 + tx] = t[tx][ty + i*8];
}

// ======== gemm_h: 128(M)x256(N) tile, BK=32, 8 waves, 48KB LDS dbuf ========
// R20 fix: swizzle f(row) = (row>>1)&3 both-sides (was (row&3): 4-way bank
// conflict, 4.19M/dispatch — 64B rows mean bank-group=(row&1)*2+slot, so the
// XOR must use row bit 1-2, covering 8 groups x 2 lanes = free).
template<int OUT_BF16, int RELU, int SPLITK>
__global__ __launch_bounds__(512)
void gemm_h(const bf16* __restrict__ A, const bf16* __restrict__ Bt,
            const float* __restrict__ bias, void* __restrict__ Cout,
            P4 part, int Ndim, int Kdim) {
  __shared__ bf16 Asm[2][128 * 32];   // 8KB x2
  __shared__ bf16 Bsm[2][256 * 32];   // 16KB x2 => 48KB
  const int gx = gridDim.x, gy = gridDim.y;
  const int gxy = gx * gy;
  const int nwg = gxy * gridDim.z;
  const int lin = (blockIdx.z * gy + blockIdx.y) * gx + blockIdx.x;
  const int swz = (lin & 7) * (nwg >> 3) + (lin >> 3);
  int bz = 0, rem = swz;
  if (SPLITK > 1) { bz = swz / gxy; rem = swz - bz * gxy; }
  const int by = rem / gx, bx = rem - by * gx;
  const int m0 = by * 128, n0 = bx * 256;
  const int tid = threadIdx.x;
  const int wave = tid >> 6, lane = tid & 63;
  const int g = lane >> 4, r = lane & 15;
  const int wr = wave >> 2, wn = wave & 3;   // 2M x 4N -> per-wave 64x64
  const int kstart = bz * (Kdim / SPLITK);

  const int lrow = lane >> 2;                        // 0..15 (staging row)
  const int lslot = (lane & 3) ^ ((lane >> 3) & 3);  // pre-swizzled: f(lrow)=(lrow>>1)&3
  const bf16* Ag = A + (size_t)(m0 + wave * 16 + lrow) * Kdim + kstart + lslot * 8;
  const bf16* Bg0 = Bt + (size_t)(n0 + wave * 32 + lrow) * Kdim + kstart + lslot * 8;
  const bf16* Bg1 = Bg0 + (size_t)16 * Kdim;

  f32x4 acc[4][4] = {};
  const int NT = (Kdim / SPLITK) >> 5;

  auto stage = [&](int t) {
    const int kb = t << 5;
    bf16* Ad = Asm[t & 1] + wave * 512;          // wave's 16 rows x 32
    bf16* Bd = Bsm[t & 1] + wave * 1024;         // wave's 32 rows x 32
    gload_lds16(Ag + kb, Ad);
    gload_lds16(Bg0 + kb, Bd);
    gload_lds16(Bg1 + kb, Bd + 512);
  };

  stage(0);
  __syncthreads();

  const int rsw = (r >> 1) & 3;   // f(row) for fragment rows (row = 16i + r)
  for (int t = 0; t < NT; ++t) {
    const bf16* Ab = Asm[t & 1];
    const bf16* Bb = Bsm[t & 1];
    bf16x8 af[4], bfr[4];
    #pragma unroll
    for (int i = 0; i < 4; ++i) {
      const int row = wr * 64 + i * 16 + r;
      af[i] = *(const bf16x8*)(Ab + row * 32 + ((g ^ rsw) * 8));
    }
    #pragma unroll
    for (int i = 0; i < 4; ++i) {
      const int rowb = wn * 64 + i * 16 + r;
      bfr[i] = *(const bf16x8*)(Bb + rowb * 32 + ((g ^ rsw) * 8));
    }
    if (t + 1 < NT) stage(t + 1);
    __builtin_amdgcn_s_setprio(1);
    #pragma unroll
    for (int i = 0; i < 4; ++i)
      #pragma unroll
      for (int jn = 0; jn < 4; ++jn)
        acc[i][jn] = mfma32(af[i], bfr[jn], acc[i][jn]);
    __builtin_amdgcn_s_setprio(0);
    __syncthreads();
  }

  #pragma unroll
  for (int mi = 0; mi < 4; ++mi) {
    #pragma unroll
    for (int ni = 0; ni < 4; ++ni) {
      const int col = n0 + wn * 64 + ni * 16 + r;
      const float bv = (SPLITK > 1) ? 0.f : bias[col];
      #pragma unroll
      for (int jj = 0; jj < 4; ++jj) {
        const int row = m0 + wr * 64 + mi * 16 + g * 4 + jj;
        float v = acc[mi][ni][jj] + bv;
        if (RELU) v = fmaxf(v, 0.f);
        if (SPLITK > 1) part.p[bz][(size_t)row * Ndim + col] = (bf16)v;
        else if (OUT_BF16) ((bf16*)Cout)[(size_t)row * Ndim + col] = (bf16)v;
        else               ((float*)Cout)[(size_t)row * Ndim + col] = v;
      }
    }
  }
}

// ======== 256x256 GEMM (R13-proven): min-LDS-read 2-phase, counted vmcnt ========
// Used for Wo/FF2 split-K=4 (R17 measured-best for those shapes).
template<int OUT_BF16, int RELU, int SPLITK>
__global__ __launch_bounds__(512)
void gemm256(const bf16* __restrict__ A, const bf16* __restrict__ Bt,
             const float* __restrict__ bias, void* __restrict__ Cout,
             P4 part, int Ndim, int Kdim) {
  __shared__ bf16 Asm[3][256 * 64];   // 96KB
  __shared__ bf16 Bsm[2][256 * 64];   // 64KB
  const int gx = gridDim.x, gy = gridDim.y;
  const int gxy = gx * gy;
  const int nwg = gxy * gridDim.z;
  const int lin = (blockIdx.z * gy + blockIdx.y) * gx + blockIdx.x;
  const int swz = (lin & 7) * (nwg >> 3) + (lin >> 3);
  int bz = 0, rem = swz;
  if (SPLITK > 1) { bz = swz / gxy; rem = swz - bz * gxy; }
  const int by = rem / gx, bx = rem - by * gx;
  const int m0 = by * 256, n0 = bx * 256;
  const int tid = threadIdx.x;
  const int wave = tid >> 6, lane = tid & 63;
  const int g = lane >> 4, r = lane & 15;
  const int wr = wave >> 2, wn = wave & 3;
  const int kstart = bz * (Kdim / SPLITK);

  const int srow = wave * 8 + (lane >> 3);
  const int skslot = (lane & 7) ^ (lane >> 3);
  const bf16* Ag = A + (size_t)(m0 + srow) * Kdim + kstart + skslot * 8;
  const bf16* Bg = Bt + (size_t)(n0 + srow) * Kdim + kstart + skslot * 8;

  f32x4 acc[8][4] = {};
  const int NT = (Kdim / SPLITK) >> 6;

  auto stageA = [&](int t) {
    if (t >= NT) return;
    const int kb = t << 6;
    bf16* Ad = Asm[t % 3];
    #pragma unroll
    for (int j = 0; j < 4; ++j)
      gload_lds16(Ag + (size_t)j * 64 * Kdim + kb, Ad + (j * 64 + wave * 8) * 64);
  };
  auto stageB = [&](int t) {
    if (t >= NT) return;
    const int kb = t << 6;
    bf16* Bd = Bsm[t & 1];
    #pragma unroll
    for (int j = 0; j < 4; ++j)
      gload_lds16(Bg + (size_t)j * 64 * Kdim + kb, Bd + (j * 64 + wave * 8) * 64);
  };

  stageA(0);
  stageB(0);
  stageA(1);
  asm volatile("s_waitcnt vmcnt(4)" ::: "memory");
  asm volatile("s_barrier" ::: "memory");

  for (int t = 0; t < NT; ++t) {
    const bf16* Ab = Asm[t % 3];
    const bf16* Bb = Bsm[t & 1];
    bf16x8 bfr[4][2];
    #pragma unroll
    for (int i = 0; i < 4; ++i) {
      const int rowb = wn * 64 + i * 16 + r;
      #pragma unroll
      for (int kk = 0; kk < 2; ++kk)
        bfr[i][kk] = *(const bf16x8*)(Bb + rowb * 64 + (((kk * 4 + g) ^ (r & 7)) * 8));
    }
    #pragma unroll
    for (int ph = 0; ph < 2; ++ph) {
      bf16x8 af[4][2];
      #pragma unroll
      for (int i = 0; i < 4; ++i) {
        const int row = wr * 128 + (ph * 4 + i) * 16 + r;
        #pragma unroll
        for (int kk = 0; kk < 2; ++kk)
          af[i][kk] = *(const bf16x8*)(Ab + row * 64 + (((kk * 4 + g) ^ (r & 7)) * 8));
      }
      if (ph == 0) stageB(t + 1);
      if (ph == 1) stageA(t + 2);
      asm volatile("s_barrier" ::: "memory");
      __builtin_amdgcn_s_setprio(1);
      #pragma unroll
      for (int i = 0; i < 4; ++i)
        #pragma unroll
        for (int jn = 0; jn < 4; ++jn)
          #pragma unroll
          for (int kk = 0; kk < 2; ++kk)
            acc[ph * 4 + i][jn] = mfma32(af[i][kk], bfr[jn][kk], acc[ph * 4 + i][jn]);
      __builtin_amdgcn_s_setprio(0);
      asm volatile("s_barrier" ::: "memory");
    }
    if (t + 1 < NT) {
      if (t + 2 < NT) asm volatile("s_waitcnt vmcnt(4)" ::: "memory");
      else            asm volatile("s_waitcnt vmcnt(0)" ::: "memory");
      asm volatile("s_barrier" ::: "memory");
    }
  }

  #pragma unroll
  for (int mi = 0; mi < 8; ++mi) {
    #pragma unroll
    for (int ni = 0; ni < 4; ++ni) {
      const int col = n0 + wn * 64 + ni * 16 + r;
      const float bv = (SPLITK > 1) ? 0.f : bias[col];
      #pragma unroll
      for (int jj = 0; jj < 4; ++jj) {
        const int row = m0 + wr * 128 + mi * 16 + g * 4 + jj;
        float v = acc[mi][ni][jj] + bv;
        if (RELU) v = fmaxf(v, 0.f);
        if (SPLITK > 1) part.p[bz][(size_t)row * Ndim + col] = (bf16)v;
        else if (OUT_BF16) ((bf16*)Cout)[(size_t)row * Ndim + col] = (bf16)v;
        else               ((float*)Cout)[(size_t)row * Ndim + col] = v;
      }
    }
  }
}

// ---------------- flash attention v8: KVBLK=128 (R19-proven) ----------------
__global__ __launch_bounds__(256)
void attn_kernel(const bf16* __restrict__ Q2d, const bf16* __restrict__ K2d,
                 const bf16* __restrict__ Vt, bf16* __restrict__ ctx) {
  __shared__ bf16 Ks[2 * 8192];   // 2 bufs x [2 krow-groups][2 halves][64][32]
  __shared__ bf16 Vs[2 * 8192];   // 2 bufs x [4 col-quarters][64][32]
  const int tid = threadIdx.x;
  const int wave = tid >> 6;
  const int lane = tid & 63;
  const int g = lane >> 4, r = lane & 15;
  const int lin = blockIdx.y * gridDim.x + blockIdx.x;   // 0..511
  const int swz = (lin & 7) * 64 + (lin >> 3);
  const int p = swz & 15;            // pair index 0..15
  const int bh = swz >> 4;           // 0..31
  const int b = bh >> 4, h = bh & 15;

  const int strow = wave * 16 + (lane >> 2);              // 0..63
  const int lslot = (lane & 3) ^ ((lane >> 3) & 3);       // pre-swizzled global slot
  const bf16* srcK0  = K2d + (size_t)(b*SS + strow) * QKVLD + h*HDIM + lslot * 8;
  const bf16* srcK1  = srcK0 + 32;
  const bf16* srcKh0 = srcK0 + (size_t)64 * QKVLD;        // krows 64..127 of step
  const bf16* srcKh1 = srcK1 + (size_t)64 * QKVLD;
  const bf16* srcV0  = Vt + ((size_t)bh*HDIM + strow) * SS + lslot * 8;
  const bf16* srcV1  = srcV0 + 32;

  auto sw = [](int row, int s) { return row * 32 + ((s ^ ((row >> 1) & 3)) * 8); };

  const int kr0 = 8 * (r >> 2) + (r & 3);      // permuted K row for S^T frag
  const int oKa0 = sw(kr0,      g), oKb0 = 2048 + oKa0;
  const int oKa1 = sw(kr0 +  4, g), oKb1 = 2048 + oKa1;
  const int oKa2 = sw(kr0 + 32, g), oKb2 = 2048 + oKa2;
  const int oKa3 = sw(kr0 + 36, g), oKb3 = 2048 + oKa3;
  int oV[4];
  #pragma unroll
  for (int c = 0; c < 4; ++c) oV[c] = sw(c * 16 + r, g);

  bf16x8 onesf;
  #pragma unroll
  for (int j = 0; j < 8; ++j) onesf[j] = (bf16)1.0f;

  #pragma unroll
  for (int tt = 0; tt < 2; ++tt) {
    const int tile = tt ? (31 - p) : p;
    const int q0 = tile * 64 + wave * 16;
    const int qg = q0 + r;
    const bf16* qp = Q2d + (size_t)(b*SS + q0 + r) * QKVLD + h * HDIM;
    const bf16x8 qf0 = *(const bf16x8*)(qp + g * 8);
    const bf16x8 qf1 = *(const bf16x8*)(qp + 32 + g * 8);
    f32x4 ov[4] = {};
    f32x4 lacc = {};                // row-sum l via ones-column MFMA
    const int nst = (tile >> 1) + 1;   // 128-krow steps
    {
      bf16* kb = Ks + wave * 512;
      bf16* vb = Vs + wave * 512;
      gload_lds16(srcK0,  kb);
      gload_lds16(srcK1,  kb + 2048);
      gload_lds16(srcKh0, kb + 4096);
      gload_lds16(srcKh1, kb + 6144);
      gload_lds16(srcV0,      vb);
      gload_lds16(srcV1,      vb + 2048);
      gload_lds16(srcV0 + 64, vb + 4096);
      gload_lds16(srcV1 + 64, vb + 6144);
    }
    __syncthreads();
    int cur = 0;
    for (int st = 0; st < nst; ++st) {
      const int k0 = st * 128;
      if (st + 1 < nst) {
        const int kn = k0 + 128;
        bf16* kb = Ks + (cur ^ 1) * 8192 + wave * 512;
        bf16* vb = Vs + (cur ^ 1) * 8192 + wave * 512;
        gload_lds16(srcK0  + (size_t)kn * QKVLD, kb);
        gload_lds16(srcK1  + (size_t)kn * QKVLD, kb + 2048);
        gload_lds16(srcKh0 + (size_t)kn * QKVLD, kb + 4096);
        gload_lds16(srcKh1 + (size_t)kn * QKVLD, kb + 6144);
        gload_lds16(srcV0 + kn,      vb);
        gload_lds16(srcV1 + kn,      vb + 2048);
        gload_lds16(srcV0 + kn + 64, vb + 4096);
        gload_lds16(srcV1 + kn + 64, vb + 6144);
      }
      const bf16* Kb = Ks + cur * 8192;
      const bf16* Vb = Vs + cur * 8192;
      f32x4 c0 = {}, c1 = {}, c2 = {}, c3 = {};
      f32x4 c4 = {}, c5 = {}, c6 = {}, c7 = {};
      __builtin_amdgcn_s_setprio(1);
      c0 = mfma32(*(const bf16x8*)(Kb + oKa0), qf0, c0);
      c1 = mfma32(*(const bf16x8*)(Kb + oKa1), qf0, c1);
      c2 = mfma32(*(const bf16x8*)(Kb + oKa2), qf0, c2);
      c3 = mfma32(*(const bf16x8*)(Kb + oKa3), qf0, c3);
      c0 = mfma32(*(const bf16x8*)(Kb + oKb0), qf1, c0);
      c1 = mfma32(*(const bf16x8*)(Kb + oKb1), qf1, c1);
      c2 = mfma32(*(const bf16x8*)(Kb + oKb2), qf1, c2);
      c3 = mfma32(*(const bf16x8*)(Kb + oKb3), qf1, c3);
      c4 = mfma32(*(const bf16x8*)(Kb + 4096 + oKa0), qf0, c4);
      c5 = mfma32(*(const bf16x8*)(Kb + 4096 + oKa1), qf0, c5);
      c6 = mfma32(*(const bf16x8*)(Kb + 4096 + oKa2), qf0, c6);
      c7 = mfma32(*(const bf16x8*)(Kb + 4096 + oKa3), qf0, c7);
      c4 = mfma32(*(const bf16x8*)(Kb + 4096 + oKb0), qf1, c4);
      c5 = mfma32(*(const bf16x8*)(Kb + 4096 + oKb1), qf1, c5);
      c6 = mfma32(*(const bf16x8*)(Kb + 4096 + oKb2), qf1, c6);
      c7 = mfma32(*(const bf16x8*)(Kb + 4096 + oKb3), qf1, c7);
      __builtin_amdgcn_s_setprio(0);
      // scores in log2 domain; masked -> 0 via exp2(-3e38)
      float p0[4], p1[4], p2[4], p3[4], p4[4], p5[4], p6[4], p7[4];
      const bool need_mask = (k0 + 127 > qg);
      #pragma unroll
      for (int j = 0; j < 4; ++j) {
        float s0 = c0[j], s1 = c1[j], s2 = c2[j], s3 = c3[j];
        float s4 = c4[j], s5 = c5[j], s6 = c6[j], s7 = c7[j];
        if (need_mask) {
          if (k0 + 8*g + j > qg)           s0 = -3.0e38f;
          if (k0 + 8*g + 4 + j > qg)       s1 = -3.0e38f;
          if (k0 + 32 + 8*g + j > qg)      s2 = -3.0e38f;
          if (k0 + 32 + 8*g + 4 + j > qg)  s3 = -3.0e38f;
          if (k0 + 64 + 8*g + j > qg)      s4 = -3.0e38f;
          if (k0 + 64 + 8*g + 4 + j > qg)  s5 = -3.0e38f;
          if (k0 + 96 + 8*g + j > qg)      s6 = -3.0e38f;
          if (k0 + 96 + 8*g + 4 + j > qg)  s7 = -3.0e38f;
        }
        p0[j] = fast_exp2(s0);
        p1[j] = fast_exp2(s1);
        p2[j] = fast_exp2(s2);
        p3[j] = fast_exp2(s3);
        p4[j] = fast_exp2(s4);
        p5[j] = fast_exp2(s5);
        p6[j] = fast_exp2(s6);
        p7[j] = fast_exp2(s7);
      }
      bf16x8 pfa, pfb, pfc, pfd;
      #pragma unroll
      for (int j = 0; j < 4; ++j) {
        pfa[j] = (bf16)p0[j]; pfa[4 + j] = (bf16)p1[j];
        pfb[j] = (bf16)p2[j]; pfb[4 + j] = (bf16)p3[j];
        pfc[j] = (bf16)p4[j]; pfc[4 + j] = (bf16)p5[j];
        pfd[j] = (bf16)p6[j]; pfd[4 + j] = (bf16)p7[j];
      }
      __builtin_amdgcn_s_setprio(1);
      #pragma unroll
      for (int c = 0; c < 4; ++c) {
        bf16x8 vfa = *(const bf16x8*)(Vb + oV[c]);
        bf16x8 vfb = *(const bf16x8*)(Vb + 2048 + oV[c]);
        bf16x8 vfc = *(const bf16x8*)(Vb + 4096 + oV[c]);
        bf16x8 vfd = *(const bf16x8*)(Vb + 6144 + oV[c]);
        ov[c] = mfma32(pfa, vfa, ov[c]);
        ov[c] = mfma32(pfb, vfb, ov[c]);
        ov[c] = mfma32(pfc, vfc, ov[c]);
        ov[c] = mfma32(pfd, vfd, ov[c]);
      }
      lacc = mfma32(pfa, onesf, lacc);
      lacc = mfma32(pfb, onesf, lacc);
      lacc = mfma32(pfc, onesf, lacc);
      lacc = mfma32(pfd, onesf, lacc);
      __builtin_amdgcn_s_setprio(0);
      __syncthreads();
      cur ^= 1;
    }
    #pragma unroll
    for (int j = 0; j < 4; ++j) {
      const float inv = 1.f / lacc[j];    // lacc[j] = l for q-row q0+4g+j
      const int row = b*SS + q0 + 4*g + j;
      #pragma unroll
      for (int c = 0; c < 4; ++c)
        ctx[(size_t)row * DD + h*HDIM + c*16 + r] = (bf16)(ov[c][j] * inv);
    }
  }
}

// ---------------- LayerNorm(a + sum(4 bf16 partials) + colbias) * g + b ----------------
template<int WRITEB>
__global__ __launch_bounds__(256)
void ln_bf4_kernel(const float* __restrict__ a, P4 part, const float* __restrict__ cb,
                   const float* __restrict__ gam, const float* __restrict__ bet,
                   float* __restrict__ outf, bf16* __restrict__ outb) {
  const int row = blockIdx.x;
  const int tid = threadIdx.x;
  const size_t base = (size_t)row * DD + tid * 4;
  float4 va = *(const float4*)(a + base);
  bf16x4 u0 = *(const bf16x4*)(part.p[0] + base);
  bf16x4 u1 = *(const bf16x4*)(part.p[1] + base);
  bf16x4 u2 = *(const bf16x4*)(part.p[2] + base);
  bf16x4 u3 = *(const bf16x4*)(part.p[3] + base);
  float4 vb4 = *(const float4*)(cb + tid * 4);
  float x0 = va.x + ((float)u0[0] + (float)u1[0]) + ((float)u2[0] + (float)u3[0]) + vb4.x;
  float x1 = va.y + ((float)u0[1] + (float)u1[1]) + ((float)u2[1] + (float)u3[1]) + vb4.y;
  float x2 = va.z + ((float)u0[2] + (float)u1[2]) + ((float)u2[2] + (float)u3[2]) + vb4.z;
  float x3 = va.w + ((float)u0[3] + (float)u1[3]) + ((float)u2[3] + (float)u3[3]) + vb4.w;
  float s  = x0 + x1 + x2 + x3;
  float s2 = x0*x0 + x1*x1 + x2*x2 + x3*x3;
  #pragma unroll
  for (int off = 32; off > 0; off >>= 1) {
    s  += __shfl_xor(s,  off);
    s2 += __shfl_xor(s2, off);
  }
  __shared__ float red[8];
  const int wv = tid >> 6;
  if ((tid & 63) == 0) { red[wv] = s; red[wv + 4] = s2; }
  __syncthreads();
  s  = red[0] + red[1] + red[2] + red[3];
  s2 = red[4] + red[5] + red[6] + red[7];
  const float mu  = s * (1.f / DD);
  const float var = s2 * (1.f / DD) - mu * mu;
  const float rs  = rsqrtf(var + 1e-5f);
  float4 vg = *(const float4*)(gam + tid * 4);
  float4 vb = *(const float4*)(bet + tid * 4);
  float y0 = (x0 - mu) * rs * vg.x + vb.x;
  float y1 = (x1 - mu) * rs * vg.y + vb.y;
  float y2 = (x2 - mu) * rs * vg.z + vb.z;
  float y3 = (x3 - mu) * rs * vg.w + vb.w;
  float4 yo; yo.x = y0; yo.y = y1; yo.z = y2; yo.w = y3;
  *(float4*)(outf + base) = yo;
  if (WRITEB) {
    bf16x4 ob;
    ob[0] = (bf16)y0; ob[1] = (bf16)y1; ob[2] = (bf16)y2; ob[3] = (bf16)y3;
    *(bf16x4*)(outb + base) = ob;
  }
}

extern "C" void kernel_launch(void* const* d_in, const int* in_sizes, int n_in,
                              void* d_out, int out_size, void* d_ws, size_t ws_size,
                              hipStream_t stream) {
  const float* src  = (const float*)d_in[0];
  const float* Wq   = (const float*)d_in[2];
  const float* bq   = (const float*)d_in[3];
  const float* Wk   = (const float*)d_in[4];
  const float* bk   = (const float*)d_in[5];
  const float* Wv   = (const float*)d_in[6];
  const float* bv   = (const float*)d_in[7];
  const float* Wo   = (const float*)d_in[8];
  const float* bo   = (const float*)d_in[9];
  const float* W1   = (const float*)d_in[10];
  const float* b1   = (const float*)d_in[11];
  const float* W2   = (const float*)d_in[12];
  const float* b2   = (const float*)d_in[13];
  const float* ln1g = (const float*)d_in[14];
  const float* ln1b = (const float*)d_in[15];
  const float* ln2g = (const float*)d_in[16];
  const float* ln2b = (const float*)d_in[17];

  char* ws = (char*)d_ws;
  const size_t MB = 1024 * 1024;
  bf16* wqkvt = (bf16*)(ws + 0 * MB);    // 6MB (dead after QKV)
  bf16* wot   = (bf16*)(ws + 6 * MB);    // 2MB (dead after Wo)
  bf16* w1t   = (bf16*)(ws + 8 * MB);    // 8MB (dead after FF1)
  bf16* w2t   = (bf16*)(ws + 16 * MB);   // 8MB (live through FF2)
  bf16* bsrc  = (bf16*)(ws + 24 * MB);   // 8MB; reused as xb (dead after FF1)
  bf16* xb    = bsrc;
  bf16* qkv   = (bf16*)(ws + 32 * MB);   // 24MB (dead after attn)
  bf16* vt    = (bf16*)(ws + 56 * MB);   // 8MB (dead after attn)
  bf16* ctx   = (bf16*)(ws + 64 * MB);   // 8MB (dead after Wo)
  bf16* ff1   = qkv;                     // [4096][4096] = 32MB, reuses qkv+vt
  float* xf   = (float*)(ws + 72 * MB);  // 16MB (live to LN2)
  float* bqkv = (float*)(ws + 88 * MB);  // 12KB
  float* outp = (float*)d_out;

  // Wo bf16 partials over dead qkv+vt region [32,64)
  P4 wop;
  wop.p[0] = (bf16*)(ws + 32 * MB);
  wop.p[1] = (bf16*)(ws + 40 * MB);
  wop.p[2] = (bf16*)(ws + 48 * MB);
  wop.p[3] = (bf16*)(ws + 56 * MB);
  // FF2 bf16 partials over regions dead at FF2 time
  P4 fp;
  fp.p[0] = (bf16*)(ws + 0 * MB);        // dead wqkvt(+wot)
  fp.p[1] = (bf16*)(ws + 8 * MB);        // dead w1t
  fp.p[2] = (bf16*)(ws + 24 * MB);       // dead xb
  fp.p[3] = (bf16*)(ws + 64 * MB);       // dead ctx

  // conversions
  cvt_bf16_kernel<<<(MR * DD) / 1024, 256, 0, stream>>>(src, bsrc, MR * DD);
  TP4 tp;
  tp.src[0] = Wq; tp.dst[0] = wqkvt;              tp.scale[0] = 0.18033688f; // 0.125*log2e
  tp.src[1] = Wk; tp.dst[1] = wqkvt + 1024*1024;  tp.scale[1] = 1.f;
  tp.src[2] = Wv; tp.dst[2] = wqkvt + 2048*1024;  tp.scale[2] = 1.f;
  tp.src[3] = Wo; tp.dst[3] = wot;                tp.scale[3] = 1.f;
  transpose_w4_kernel<<<dim3(32, 32, 4), 256, 0, stream>>>(tp);
  transpose_w_kernel<<<dim3(128, 32), 256, 0, stream>>>(W1, w1t, DD, FFD);
  transpose_w_kernel<<<dim3(32, 128), 256, 0, stream>>>(W2, w2t, FFD, DD);
  concat_bias_kernel<<<12, 256, 0, stream>>>(bq, bk, bv, bqkv);

  // fused QKV projection: 128x256 tiles, 384 blocks (1.5/CU)
  gemm_h<1, 0, 1><<<dim3(QKVLD / 256, MR / 128), 512, 0, stream>>>(bsrc, wqkvt, bqkv, qkv, P4{}, QKVLD, DD);
  transpose_v_kernel<<<dim3(SS / 32, HDIM / 32, BB * HH), 256, 0, stream>>>(qkv + 2048, vt);

  // attention (Q at col 0, K at col 1024 of qkv); 512 blocks, pair of tiles each
  attn_kernel<<<dim3(16, BB * HH), 256, 0, stream>>>(qkv, qkv + 1024, vt, ctx);

  // output projection: gemm256 split-K=4 (R17 measured-best); reduce+bias in LN1
  gemm256<0, 0, 4><<<dim3(DD / 256, MR / 256, 4), 512, 0, stream>>>(ctx, wot, nullptr, nullptr, wop, DD, DD);
  ln_bf4_kernel<1><<<MR, 256, 0, stream>>>(src, wop, bo, ln1g, ln1b, xf, xb);

  // FFN: FF1 128x256 tiles, 512 blocks (2/CU); FF2 gemm256 split-K=4
  gemm_h<1, 1, 1><<<dim3(FFD / 256, MR / 128), 512, 0, stream>>>(xb, w1t, b1, ff1, P4{}, FFD, DD);
  gemm256<0, 0, 4><<<dim3(DD / 256, MR / 256, 4), 512, 0, stream>>>(ff1, w2t, nullptr, nullptr, fp, DD, FFD);
  ln_bf4_kernel<0><<<MR, 256, 0, stream>>>(xf, fp, b2, ln2g, ln2b, outp, nullptr);
}